// Round 8
// baseline (183.153 us; speedup 1.0000x reference)
//
#include <hip/hip_runtime.h>

// SparseAttention, MFMA bf16 flash-style, split-kv in-block, pre-converted kv.
// B=1 S=2048 H=16 D=128 WIN=512 RATIO=4; kv shared across heads.
// Kernel A: concat(kv_states, kv_compress) -> bf16 in d_ws (2592 rows, tail 0).
// Kernel B: block = 4 queries x 8 heads (M=32), 4 waves = 2 kv-splits x 2 m-tiles.
// Split s does kv tiles {s, s+2, ...}; splits merge (m,l,O) via LDS at end.
// Swapped MFMAs: T = K*Q^T (C col=lm=m, row=kv), O^T = V^T*P (C col=m, row=d).
// R8: K-operand lives in REGISTERS (kfrag), global-loaded one split-iteration
// ahead (issued right after the QK MFMAs consume the previous set) -> K loads
// are off the critical path (R7's mistake), and Ksub LDS staging stays deleted.
// KT (V^T) staging + v_perm repack + masks + merge: R5/R7-verified paths.

typedef __attribute__((ext_vector_type(8))) short bf16x8;
typedef __attribute__((ext_vector_type(4))) float f32x4;
typedef unsigned short u16;
typedef unsigned int u32;

constexpr int S = 2048, H = 16, D = 128, WIN = 512;
constexpr int QB = 4, HG = 8;   // M = 32
constexpr int NT = 256;         // 4 waves
constexpr int KVROWS = 2592;    // 2048 window + 512 compressed + 32 zero pad

__device__ __forceinline__ u16 f2bf(float f) {
  u32 u = __builtin_bit_cast(u32, f);
  return (u16)((u + 0x7FFFu + ((u >> 16) & 1u)) >> 16);
}

// ---- Kernel A: kv fp32 -> bf16 concat+pad into ws ----
__global__ __launch_bounds__(256) void precvt_kv(
    const float* __restrict__ kvs, const float* __restrict__ kvc,
    u16* __restrict__ dst) {
  int idx = blockIdx.x * 256 + threadIdx.x;      // one per 8 elements
  if (idx >= KVROWS * (D / 8)) return;
  int row = idx >> 4, c8 = (idx & 15) * 8;
  float4 a = make_float4(0.f, 0.f, 0.f, 0.f), b = a;
  if (row < 2048) {
    const float4* p = (const float4*)(kvs + (size_t)row * D + c8);
    a = p[0]; b = p[1];
  } else if (row < 2560) {
    const float4* p = (const float4*)(kvc + (size_t)(row - 2048) * D + c8);
    a = p[0]; b = p[1];
  }
  bf16x8 v;
  v[0] = (short)f2bf(a.x); v[1] = (short)f2bf(a.y);
  v[2] = (short)f2bf(a.z); v[3] = (short)f2bf(a.w);
  v[4] = (short)f2bf(b.x); v[5] = (short)f2bf(b.y);
  v[6] = (short)f2bf(b.z); v[7] = (short)f2bf(b.w);
  *(bf16x8*)(dst + (size_t)row * D + c8) = v;
}

// ---- Kernel B: attention ----
__global__ __launch_bounds__(NT, 4) void sparse_attn_mfma6(
    const float* __restrict__ q, const u16* __restrict__ kvb,
    const float* __restrict__ sink, float* __restrict__ out) {

  const int it = (int)(gridDim.x - 1u - blockIdx.x);  // big-i blocks first
  const int i0 = it * QB;
  const int h0 = blockIdx.y * HG;
  const int tid = threadIdx.x;
  const int wave = tid >> 6, lane = tid & 63;
  const int split = wave >> 1, mtg = wave & 1;
  const int lm = lane & 15, lg = lane >> 4;

  // LDS: KT 2x10240 | Pll 4x1280 = 25600 B
  __shared__ __align__(16) char smem[25600];
  u16 (*KTl)[40] = (u16(*)[40])(smem + split * 10240);
  u16 (*Pll)[40] = (u16(*)[40])(smem + 20480 + wave * 1280);

  const int iq = i0 + (lm & 3);
  const int hh = h0 + mtg * 4 + (lm >> 2);

  // ---- Q fragments (B-operand: col=lm=m, k=lg*8+j) ----
  const float qscale = 0.08838834764831845f;  // 1/sqrt(128)
  bf16x8 qf[4];
  {
    const float* qp = q + ((size_t)iq * H + hh) * D;
#pragma unroll
    for (int kt = 0; kt < 4; ++kt) {
      const float4* p4 = (const float4*)(qp + kt * 32 + lg * 8);
      float4 a = p4[0], b = p4[1];
      bf16x8 v;
      v[0] = (short)f2bf(a.x * qscale); v[1] = (short)f2bf(a.y * qscale);
      v[2] = (short)f2bf(a.z * qscale); v[3] = (short)f2bf(a.w * qscale);
      v[4] = (short)f2bf(b.x * qscale); v[5] = (short)f2bf(b.y * qscale);
      v[6] = (short)f2bf(b.z * qscale); v[7] = (short)f2bf(b.w * qscale);
      qf[kt] = v;
    }
  }

  const float sk = sink[hh];
  float m_run = sk, l_run = 0.f;
  f32x4 oacc[8];
  const f32x4 fzero = {0.f, 0.f, 0.f, 0.f};
#pragma unroll
  for (int b = 0; b < 8; ++b) oacc[b] = fzero;

  // ---- kv tiling ----
  const int w_lo = (i0 > WIN - 1) ? (i0 - (WIN - 1)) : 0;
  const int n1r = i0 + QB - w_lo;     // window rows (<=515)
  const int n2r = (i0 + QB) >> 2;     // compressed rows
  const int nt1 = (n1r + 31) >> 5;
  const int nt2 = (n2r + 31) >> 5;
  const int ntiles = nt1 + nt2;       // >= 2 always
  const int kmax = (ntiles + 1) >> 1;

  // staging: each split's 128 threads cover 32 rows x 128 cols
  const int st = tid & 127;
  const int st_t7 = st & 7, st_r0 = st_t7 * 4, st_dc = st >> 3;  // dc 0..15

  uint4 sreg[4];    // V staging regs (4 rows x 8 bf16)
  bf16x8 kfrag[8];  // K A-frags: [kt]=rows arow+lm, [4+kt]=rows arow+16+lm

  auto sload = [&](int tt) {
    const int row0 = (tt < nt1) ? (w_lo + tt * 32) : (2048 + (tt - nt1) * 32);
    const u16* p = kvb + (size_t)(row0 + st_r0) * D + st_dc * 8;
#pragma unroll
    for (int rr = 0; rr < 4; ++rr)
      sreg[rr] = *(const uint4*)(p + (size_t)rr * D);
  };

  auto kload = [&](int tt) {
    const int arow = (tt < nt1) ? (w_lo + tt * 32) : (2048 + (tt - nt1) * 32);
    const u16* kA = kvb + (size_t)(arow + lm) * D + lg * 8;
#pragma unroll
    for (int kt = 0; kt < 4; ++kt) {
      kfrag[kt]     = *(const bf16x8*)(kA + kt * 32);
      kfrag[4 + kt] = *(const bf16x8*)(kA + 16 * D + kt * 32);
    }
  };

  auto swrite = [&]() {   // KT (V^T) staging, d-XOR, v_perm repack (verified)
    const u32* R0 = (const u32*)&sreg[0];
    const u32* R1 = (const u32*)&sreg[1];
    const u32* R2 = (const u32*)&sreg[2];
    const u32* R3 = (const u32*)&sreg[3];
#pragma unroll
    for (int dd2 = 0; dd2 < 4; ++dd2) {
#pragma unroll
      for (int h = 0; h < 2; ++h) {
        const u32 sel = h ? 0x07060302u : 0x05040100u;
        u32 lo = __builtin_amdgcn_perm(R1[dd2], R0[dd2], sel);
        u32 hi = __builtin_amdgcn_perm(R3[dd2], R2[dd2], sel);
        int dl = st_dc * 8 + dd2 * 2 + h;
        int dphys = (dl & ~7) | ((dl & 7) ^ (st_dc & 7));
        *(uint2*)&KTl[dphys][st_r0] = make_uint2(lo, hi);
      }
    }
  };

  kload(split);  // prologue: K frags for first owned tile
  sload(split);  // prologue: V rows for first owned tile

  for (int k = 0; k < kmax; ++k) {
    const int tt = 2 * k + split;
    const bool active = tt < ntiles;     // wave-uniform
    __syncthreads();                     // KT buffer free (prev tile consumed)
    if (active) swrite();                // stage V^T for this tile
    const int tn = tt + 2;
    if (tn < ntiles) sload(tn);          // prefetch next V tile

    // ---- T = K·Q^T (pure register MFMA; kfrag prefetched last iter) ----
    f32x4 tacc[2];
    tacc[0] = fzero; tacc[1] = fzero;
    if (active) {
      __builtin_amdgcn_s_setprio(1);
#pragma unroll
      for (int kt = 0; kt < 4; ++kt) {
        tacc[0] = __builtin_amdgcn_mfma_f32_16x16x32_bf16(kfrag[kt], qf[kt], tacc[0], 0, 0, 0);
        tacc[1] = __builtin_amdgcn_mfma_f32_16x16x32_bf16(kfrag[4 + kt], qf[kt], tacc[1], 0, 0, 0);
      }
      __builtin_amdgcn_s_setprio(0);
    }
    if (tn < ntiles) kload(tn);          // refill kfrag for tt+2 (hidden by
                                         // softmax+PV+barriers until next QK)
    __syncthreads();                     // staged KT visible
    if (!active) continue;               // barrier counts stay matched

    const bool isw = tt < nt1;
    const int row0 = isw ? (w_lo + tt * 32) : ((tt - nt1) * 32);  // mask-space

    // ---- mask (wave-uniform fast path) + online softmax (state at lane=m) ----
    float vv[8];
    float tm = -1e30f;
    const bool fullv = isw ? (row0 >= i0 + 3 - (WIN - 1)) && (row0 + 31 <= i0)
                           : ((row0 + 31) * 4 + 3 <= i0);
    if (fullv) {
#pragma unroll
      for (int k2 = 0; k2 < 2; ++k2)
#pragma unroll
        for (int r = 0; r < 4; ++r) {
          float x = tacc[k2][r];
          vv[k2 * 4 + r] = x;
          tm = fmaxf(tm, x);
        }
    } else {
#pragma unroll
      for (int k2 = 0; k2 < 2; ++k2)
#pragma unroll
        for (int r = 0; r < 4; ++r) {
          int jj = row0 + k2 * 16 + lg * 4 + r;
          float x = tacc[k2][r];
          bool ok = isw ? (jj <= iq && jj + WIN > iq) : (jj * 4 + 3 <= iq);
          x = ok ? x : -1e30f;
          vv[k2 * 4 + r] = x;
          tm = fmaxf(tm, x);
        }
    }
    tm = fmaxf(tm, __shfl_xor(tm, 16));
    tm = fmaxf(tm, __shfl_xor(tm, 32));
    if (__any(tm > m_run + 8.f)) {       // defer-max (T13)
      float mn = fmaxf(m_run, tm);
      float fs = __expf(m_run - mn);
      m_run = mn; l_run *= fs;
#pragma unroll
      for (int dt = 0; dt < 8; ++dt) oacc[dt] *= fs;
    }
    float s = 0.f;
#pragma unroll
    for (int k2 = 0; k2 < 2; ++k2) {
      u16 pb[4];
#pragma unroll
      for (int r = 0; r < 4; ++r) {
        float p = __expf(vv[k2 * 4 + r] - m_run);
        s += p; pb[r] = f2bf(p);
      }
      *(uint2*)&Pll[lm][k2 * 16 + lg * 4] =
          make_uint2((u32)pb[0] | ((u32)pb[1] << 16),
                     (u32)pb[2] | ((u32)pb[3] << 16));
    }
    l_run += s;

    // ---- O^T += V^T·P ----
    bf16x8 pf = *(const bf16x8*)&Pll[lm][lg * 8];
    __builtin_amdgcn_s_setprio(1);
#pragma unroll
    for (int dt = 0; dt < 8; ++dt) {
      int d = dt * 16 + lm;
      int drow = (d & ~7) | ((d & 7) ^ ((d >> 3) & 7));
      bf16x8 vf = *(const bf16x8*)&KTl[drow][lg * 8];
      oacc[dt] = __builtin_amdgcn_mfma_f32_16x16x32_bf16(vf, pf, oacc[dt], 0, 0, 0);
    }
    __builtin_amdgcn_s_setprio(0);
  }

  // ---- split merge (overlay on KT region; dead now) ----
  float l = l_run;
  l += __shfl_xor(l, 16);
  l += __shfl_xor(l, 32);

  float (*Ocomb)[16][128] = (float(*)[16][128])(smem);   // 16 KB
  float* Mcomb = (float*)(smem + 16384);
  float* Lcomb = (float*)(smem + 16384 + 128);

  __syncthreads();   // all compute done before overlay writes
  if (split == 1) {
#pragma unroll
    for (int dt = 0; dt < 8; ++dt)
      *(f32x4*)&Ocomb[mtg][lm][dt * 16 + lg * 4] = oacc[dt];
    if (lg == 0) { Mcomb[mtg * 16 + lm] = m_run; Lcomb[mtg * 16 + lm] = l; }
  }
  __syncthreads();
  if (split == 0) {
    float m1 = Mcomb[mtg * 16 + lm], l1 = Lcomb[mtg * 16 + lm];
    float mf = fmaxf(m_run, m1);
    float a0 = __expf(m_run - mf), a1 = __expf(m1 - mf);
    float lf = l * a0 + l1 * a1 + __expf(sk - mf);  // sink joins denom once
    float di = 1.f / lf;
    float* op = out + ((size_t)iq * H + hh) * D;
#pragma unroll
    for (int dt = 0; dt < 8; ++dt) {
      f32x4 o1 = *(f32x4*)&Ocomb[mtg][lm][dt * 16 + lg * 4];
      float4 w4 = make_float4((oacc[dt][0] * a0 + o1[0] * a1) * di,
                              (oacc[dt][1] * a0 + o1[1] * a1) * di,
                              (oacc[dt][2] * a0 + o1[2] * a1) * di,
                              (oacc[dt][3] * a0 + o1[3] * a1) * di);
      *(float4*)(op + dt * 16 + lg * 4) = w4;
    }
  }
}

extern "C" void kernel_launch(void* const* d_in, const int* in_sizes, int n_in,
                              void* d_out, int out_size, void* d_ws, size_t ws_size,
                              hipStream_t stream) {
  const float* q    = (const float*)d_in[0];
  const float* kvs  = (const float*)d_in[1];
  const float* sink = (const float*)d_in[2];
  const float* kvc  = (const float*)d_in[3];
  float* out = (float*)d_out;
  u16* kvb = (u16*)d_ws;   // 2592*128*2 = 663,552 B

  {
    int nthr = KVROWS * (D / 8);
    precvt_kv<<<(nthr + 255) / 256, 256, 0, stream>>>(kvs, kvc, kvb);
  }
  dim3 grid(S / QB, H / HG);   // 512 x 2 = 1024 blocks
  sparse_attn_mfma6<<<grid, NT, 0, stream>>>(q, kvb, sink, out);
}

// Round 9
// 149.457 us; speedup vs baseline: 1.2255x; 1.2255x over previous
//
#include <hip/hip_runtime.h>

// SparseAttention, MFMA bf16 flash-style, split-kv in-block, pre-converted kv.
// B=1 S=2048 H=16 D=128 WIN=512 RATIO=4; kv shared across heads.
// Kernel A: concat(kv_states, kv_compress) -> bf16 in d_ws (2592 rows, tail 0).
// Kernel B: block = 4 queries x 8 heads (M=32), 4 waves = 2 kv-splits x 2 m-tiles.
// Split s does kv tiles {s, s+2, ...}; splits merge (m,l,O) via LDS at end.
// Swapped MFMAs: T = K*Q^T (C col=lm=m, row=kv), O^T = V^T*P (C col=m, row=d).
// R9 = R8 with __launch_bounds__(256,3): R8's (256,4) capped unified
// VGPR+AGPR at 128 -> kfrag spilled to scratch (VGPR=64, +31MB writes).
// K-operand in registers (kfrag), loaded one split-iteration ahead;
// KT (V^T) staging + v_perm repack + masks + merge: R5/R7-verified paths.

typedef __attribute__((ext_vector_type(8))) short bf16x8;
typedef __attribute__((ext_vector_type(4))) float f32x4;
typedef unsigned short u16;
typedef unsigned int u32;

constexpr int S = 2048, H = 16, D = 128, WIN = 512;
constexpr int QB = 4, HG = 8;   // M = 32
constexpr int NT = 256;         // 4 waves
constexpr int KVROWS = 2592;    // 2048 window + 512 compressed + 32 zero pad

__device__ __forceinline__ u16 f2bf(float f) {
  u32 u = __builtin_bit_cast(u32, f);
  return (u16)((u + 0x7FFFu + ((u >> 16) & 1u)) >> 16);
}

// ---- Kernel A: kv fp32 -> bf16 concat+pad into ws ----
__global__ __launch_bounds__(256) void precvt_kv(
    const float* __restrict__ kvs, const float* __restrict__ kvc,
    u16* __restrict__ dst) {
  int idx = blockIdx.x * 256 + threadIdx.x;      // one per 8 elements
  if (idx >= KVROWS * (D / 8)) return;
  int row = idx >> 4, c8 = (idx & 15) * 8;
  float4 a = make_float4(0.f, 0.f, 0.f, 0.f), b = a;
  if (row < 2048) {
    const float4* p = (const float4*)(kvs + (size_t)row * D + c8);
    a = p[0]; b = p[1];
  } else if (row < 2560) {
    const float4* p = (const float4*)(kvc + (size_t)(row - 2048) * D + c8);
    a = p[0]; b = p[1];
  }
  bf16x8 v;
  v[0] = (short)f2bf(a.x); v[1] = (short)f2bf(a.y);
  v[2] = (short)f2bf(a.z); v[3] = (short)f2bf(a.w);
  v[4] = (short)f2bf(b.x); v[5] = (short)f2bf(b.y);
  v[6] = (short)f2bf(b.z); v[7] = (short)f2bf(b.w);
  *(bf16x8*)(dst + (size_t)row * D + c8) = v;
}

// ---- Kernel B: attention ----
__global__ __launch_bounds__(NT, 3) void sparse_attn_mfma7(
    const float* __restrict__ q, const u16* __restrict__ kvb,
    const float* __restrict__ sink, float* __restrict__ out) {

  const int it = (int)(gridDim.x - 1u - blockIdx.x);  // big-i blocks first
  const int i0 = it * QB;
  const int h0 = blockIdx.y * HG;
  const int tid = threadIdx.x;
  const int wave = tid >> 6, lane = tid & 63;
  const int split = wave >> 1, mtg = wave & 1;
  const int lm = lane & 15, lg = lane >> 4;

  // LDS: KT 2x10240 | Pll 4x1280 = 25600 B
  __shared__ __align__(16) char smem[25600];
  u16 (*KTl)[40] = (u16(*)[40])(smem + split * 10240);
  u16 (*Pll)[40] = (u16(*)[40])(smem + 20480 + wave * 1280);

  const int iq = i0 + (lm & 3);
  const int hh = h0 + mtg * 4 + (lm >> 2);

  // ---- Q fragments (B-operand: col=lm=m, k=lg*8+j) ----
  const float qscale = 0.08838834764831845f;  // 1/sqrt(128)
  bf16x8 qf[4];
  {
    const float* qp = q + ((size_t)iq * H + hh) * D;
#pragma unroll
    for (int kt = 0; kt < 4; ++kt) {
      const float4* p4 = (const float4*)(qp + kt * 32 + lg * 8);
      float4 a = p4[0], b = p4[1];
      bf16x8 v;
      v[0] = (short)f2bf(a.x * qscale); v[1] = (short)f2bf(a.y * qscale);
      v[2] = (short)f2bf(a.z * qscale); v[3] = (short)f2bf(a.w * qscale);
      v[4] = (short)f2bf(b.x * qscale); v[5] = (short)f2bf(b.y * qscale);
      v[6] = (short)f2bf(b.z * qscale); v[7] = (short)f2bf(b.w * qscale);
      qf[kt] = v;
    }
  }

  const float sk = sink[hh];
  float m_run = sk, l_run = 0.f;
  f32x4 oacc[8];
  const f32x4 fzero = {0.f, 0.f, 0.f, 0.f};
#pragma unroll
  for (int b = 0; b < 8; ++b) oacc[b] = fzero;

  // ---- kv tiling ----
  const int w_lo = (i0 > WIN - 1) ? (i0 - (WIN - 1)) : 0;
  const int n1r = i0 + QB - w_lo;     // window rows (<=515)
  const int n2r = (i0 + QB) >> 2;     // compressed rows
  const int nt1 = (n1r + 31) >> 5;
  const int nt2 = (n2r + 31) >> 5;
  const int ntiles = nt1 + nt2;       // >= 2 always
  const int kmax = (ntiles + 1) >> 1;

  // staging: each split's 128 threads cover 32 rows x 128 cols
  const int st = tid & 127;
  const int st_t7 = st & 7, st_r0 = st_t7 * 4, st_dc = st >> 3;  // dc 0..15

  uint4 sreg[4];    // V staging regs (4 rows x 8 bf16)
  bf16x8 kfrag[8];  // K A-frags: [kt]=rows arow+lm, [4+kt]=rows arow+16+lm

  auto sload = [&](int tt) {
    const int row0 = (tt < nt1) ? (w_lo + tt * 32) : (2048 + (tt - nt1) * 32);
    const u16* p = kvb + (size_t)(row0 + st_r0) * D + st_dc * 8;
#pragma unroll
    for (int rr = 0; rr < 4; ++rr)
      sreg[rr] = *(const uint4*)(p + (size_t)rr * D);
  };

  auto kload = [&](int tt) {
    const int arow = (tt < nt1) ? (w_lo + tt * 32) : (2048 + (tt - nt1) * 32);
    const u16* kA = kvb + (size_t)(arow + lm) * D + lg * 8;
#pragma unroll
    for (int kt = 0; kt < 4; ++kt) {
      kfrag[kt]     = *(const bf16x8*)(kA + kt * 32);
      kfrag[4 + kt] = *(const bf16x8*)(kA + 16 * D + kt * 32);
    }
  };

  auto swrite = [&]() {   // KT (V^T) staging, d-XOR, v_perm repack (verified)
    const u32* R0 = (const u32*)&sreg[0];
    const u32* R1 = (const u32*)&sreg[1];
    const u32* R2 = (const u32*)&sreg[2];
    const u32* R3 = (const u32*)&sreg[3];
#pragma unroll
    for (int dd2 = 0; dd2 < 4; ++dd2) {
#pragma unroll
      for (int h = 0; h < 2; ++h) {
        const u32 sel = h ? 0x07060302u : 0x05040100u;
        u32 lo = __builtin_amdgcn_perm(R1[dd2], R0[dd2], sel);
        u32 hi = __builtin_amdgcn_perm(R3[dd2], R2[dd2], sel);
        int dl = st_dc * 8 + dd2 * 2 + h;
        int dphys = (dl & ~7) | ((dl & 7) ^ (st_dc & 7));
        *(uint2*)&KTl[dphys][st_r0] = make_uint2(lo, hi);
      }
    }
  };

  kload(split);  // prologue: K frags for first owned tile
  sload(split);  // prologue: V rows for first owned tile

  for (int k = 0; k < kmax; ++k) {
    const int tt = 2 * k + split;
    const bool active = tt < ntiles;     // wave-uniform
    __syncthreads();                     // KT buffer free (prev tile consumed)
    if (active) swrite();                // stage V^T for this tile
    const int tn = tt + 2;
    if (tn < ntiles) sload(tn);          // prefetch next V tile

    // ---- T = K·Q^T (pure register MFMA; kfrag prefetched last iter) ----
    f32x4 tacc[2];
    tacc[0] = fzero; tacc[1] = fzero;
    if (active) {
      __builtin_amdgcn_s_setprio(1);
#pragma unroll
      for (int kt = 0; kt < 4; ++kt) {
        tacc[0] = __builtin_amdgcn_mfma_f32_16x16x32_bf16(kfrag[kt], qf[kt], tacc[0], 0, 0, 0);
        tacc[1] = __builtin_amdgcn_mfma_f32_16x16x32_bf16(kfrag[4 + kt], qf[kt], tacc[1], 0, 0, 0);
      }
      __builtin_amdgcn_s_setprio(0);
    }
    if (tn < ntiles) kload(tn);          // refill kfrag for tt+2 (hidden by
                                         // softmax+PV+barriers until next QK)
    __syncthreads();                     // staged KT visible
    if (!active) continue;               // barrier counts stay matched

    const bool isw = tt < nt1;
    const int row0 = isw ? (w_lo + tt * 32) : ((tt - nt1) * 32);  // mask-space

    // ---- mask (wave-uniform fast path) + online softmax (state at lane=m) ----
    float vv[8];
    float tm = -1e30f;
    const bool fullv = isw ? (row0 >= i0 + 3 - (WIN - 1)) && (row0 + 31 <= i0)
                           : ((row0 + 31) * 4 + 3 <= i0);
    if (fullv) {
#pragma unroll
      for (int k2 = 0; k2 < 2; ++k2)
#pragma unroll
        for (int r = 0; r < 4; ++r) {
          float x = tacc[k2][r];
          vv[k2 * 4 + r] = x;
          tm = fmaxf(tm, x);
        }
    } else {
#pragma unroll
      for (int k2 = 0; k2 < 2; ++k2)
#pragma unroll
        for (int r = 0; r < 4; ++r) {
          int jj = row0 + k2 * 16 + lg * 4 + r;
          float x = tacc[k2][r];
          bool ok = isw ? (jj <= iq && jj + WIN > iq) : (jj * 4 + 3 <= iq);
          x = ok ? x : -1e30f;
          vv[k2 * 4 + r] = x;
          tm = fmaxf(tm, x);
        }
    }
    tm = fmaxf(tm, __shfl_xor(tm, 16));
    tm = fmaxf(tm, __shfl_xor(tm, 32));
    if (__any(tm > m_run + 8.f)) {       // defer-max (T13)
      float mn = fmaxf(m_run, tm);
      float fs = __expf(m_run - mn);
      m_run = mn; l_run *= fs;
#pragma unroll
      for (int dt = 0; dt < 8; ++dt) oacc[dt] *= fs;
    }
    float s = 0.f;
#pragma unroll
    for (int k2 = 0; k2 < 2; ++k2) {
      u16 pb[4];
#pragma unroll
      for (int r = 0; r < 4; ++r) {
        float p = __expf(vv[k2 * 4 + r] - m_run);
        s += p; pb[r] = f2bf(p);
      }
      *(uint2*)&Pll[lm][k2 * 16 + lg * 4] =
          make_uint2((u32)pb[0] | ((u32)pb[1] << 16),
                     (u32)pb[2] | ((u32)pb[3] << 16));
    }
    l_run += s;

    // ---- O^T += V^T·P ----
    bf16x8 pf = *(const bf16x8*)&Pll[lm][lg * 8];
    __builtin_amdgcn_s_setprio(1);
#pragma unroll
    for (int dt = 0; dt < 8; ++dt) {
      int d = dt * 16 + lm;
      int drow = (d & ~7) | ((d & 7) ^ ((d >> 3) & 7));
      bf16x8 vf = *(const bf16x8*)&KTl[drow][lg * 8];
      oacc[dt] = __builtin_amdgcn_mfma_f32_16x16x32_bf16(vf, pf, oacc[dt], 0, 0, 0);
    }
    __builtin_amdgcn_s_setprio(0);
  }

  // ---- split merge (overlay on KT region; dead now) ----
  float l = l_run;
  l += __shfl_xor(l, 16);
  l += __shfl_xor(l, 32);

  float (*Ocomb)[16][128] = (float(*)[16][128])(smem);   // 16 KB
  float* Mcomb = (float*)(smem + 16384);
  float* Lcomb = (float*)(smem + 16384 + 128);

  __syncthreads();   // all compute done before overlay writes
  if (split == 1) {
#pragma unroll
    for (int dt = 0; dt < 8; ++dt)
      *(f32x4*)&Ocomb[mtg][lm][dt * 16 + lg * 4] = oacc[dt];
    if (lg == 0) { Mcomb[mtg * 16 + lm] = m_run; Lcomb[mtg * 16 + lm] = l; }
  }
  __syncthreads();
  if (split == 0) {
    float m1 = Mcomb[mtg * 16 + lm], l1 = Lcomb[mtg * 16 + lm];
    float mf = fmaxf(m_run, m1);
    float a0 = __expf(m_run - mf), a1 = __expf(m1 - mf);
    float lf = l * a0 + l1 * a1 + __expf(sk - mf);  // sink joins denom once
    float di = 1.f / lf;
    float* op = out + ((size_t)iq * H + hh) * D;
#pragma unroll
    for (int dt = 0; dt < 8; ++dt) {
      f32x4 o1 = *(f32x4*)&Ocomb[mtg][lm][dt * 16 + lg * 4];
      float4 w4 = make_float4((oacc[dt][0] * a0 + o1[0] * a1) * di,
                              (oacc[dt][1] * a0 + o1[1] * a1) * di,
                              (oacc[dt][2] * a0 + o1[2] * a1) * di,
                              (oacc[dt][3] * a0 + o1[3] * a1) * di);
      *(float4*)(op + dt * 16 + lg * 4) = w4;
    }
  }
}

extern "C" void kernel_launch(void* const* d_in, const int* in_sizes, int n_in,
                              void* d_out, int out_size, void* d_ws, size_t ws_size,
                              hipStream_t stream) {
  const float* q    = (const float*)d_in[0];
  const float* kvs  = (const float*)d_in[1];
  const float* sink = (const float*)d_in[2];
  const float* kvc  = (const float*)d_in[3];
  float* out = (float*)d_out;
  u16* kvb = (u16*)d_ws;   // 2592*128*2 = 663,552 B

  {
    int nthr = KVROWS * (D / 8);
    precvt_kv<<<(nthr + 255) / 256, 256, 0, stream>>>(kvs, kvc, kvb);
  }
  dim3 grid(S / QB, H / HG);   // 512 x 2 = 1024 blocks
  sparse_attn_mfma7<<<grid, NT, 0, stream>>>(q, kvb, sink, out);
}

// Round 11
// 111.713 us; speedup vs baseline: 1.6395x; 1.3379x over previous
//
#include <hip/hip_runtime.h>

// SparseAttention, MFMA bf16 flash-style, pre-converted kv, big tiles.
// B=1 S=2048 H=16 D=128 WIN=512 RATIO=4; kv shared across heads.
// Kernel A: concat(kv_states, kv_compress) -> bf16 in d_ws (2592 rows, tail 0).
// Kernel B (R10): block = 8 queries x 8 heads (M=64), 4 waves, each wave owns
// one 16-row m-tile (hh = h0 + wave*2 + (lm>>3), iq = i0 + (lm&7)).
// KVBLK=64, single LDS buffer, 2 barriers/tile, ~13 tiles/block, no split/merge.
// Swapped MFMAs: T = K*Q^T (C col=lm=m, row=kv), O^T = V^T*P (C col=m, row=d).
// Ksub[kvgrp=kv/4][dgrp=d/16][4][16] row-XOR (QK A-frags), KT[d][72] d-XOR
// (PV A-frags via v_perm repack), Pll per wave. All data paths R5-verified.

typedef __attribute__((ext_vector_type(8))) short bf16x8;
typedef __attribute__((ext_vector_type(4))) float f32x4;
typedef unsigned short u16;
typedef unsigned int u32;

constexpr int S = 2048, H = 16, D = 128, WIN = 512;
constexpr int QB = 8, HG = 8;   // M = 64
constexpr int NT = 256;         // 4 waves
constexpr int KVB = 64;         // kv rows per tile
constexpr int KVROWS = 2592;    // 2048 window + 512 compressed + 32 zero pad

__device__ __forceinline__ u16 f2bf(float f) {
  u32 u = __builtin_bit_cast(u32, f);
  return (u16)((u + 0x7FFFu + ((u >> 16) & 1u)) >> 16);
}

// ---- Kernel A: kv fp32 -> bf16 concat+pad into ws ----
__global__ __launch_bounds__(256) void precvt_kv(
    const float* __restrict__ kvs, const float* __restrict__ kvc,
    u16* __restrict__ dst) {
  int idx = blockIdx.x * 256 + threadIdx.x;      // one per 8 elements
  if (idx >= KVROWS * (D / 8)) return;
  int row = idx >> 4, c8 = (idx & 15) * 8;
  float4 a = make_float4(0.f, 0.f, 0.f, 0.f), b = a;
  if (row < 2048) {
    const float4* p = (const float4*)(kvs + (size_t)row * D + c8);
    a = p[0]; b = p[1];
  } else if (row < 2560) {
    const float4* p = (const float4*)(kvc + (size_t)(row - 2048) * D + c8);
    a = p[0]; b = p[1];
  }
  bf16x8 v;
  v[0] = (short)f2bf(a.x); v[1] = (short)f2bf(a.y);
  v[2] = (short)f2bf(a.z); v[3] = (short)f2bf(a.w);
  v[4] = (short)f2bf(b.x); v[5] = (short)f2bf(b.y);
  v[6] = (short)f2bf(b.z); v[7] = (short)f2bf(b.w);
  *(bf16x8*)(dst + (size_t)row * D + c8) = v;
}

// ---- Kernel B: attention ----
__global__ __launch_bounds__(NT, 3) void sparse_attn_mfma8(
    const float* __restrict__ q, const u16* __restrict__ kvb,
    const float* __restrict__ sink, float* __restrict__ out) {

  const int it = (int)(gridDim.x - 1u - blockIdx.x);  // big-i blocks first
  const int i0 = it * QB;
  const int h0 = blockIdx.y * HG;
  const int tid = threadIdx.x;
  const int wave = tid >> 6, lane = tid & 63;
  const int lm = lane & 15, lg = lane >> 4;

  // LDS: Ksub 16KB | KT 18KB | Pll 4x2.25KB = 44,032 B total
  __shared__ __align__(16) u16 Ksub[16][8][4][16];
  __shared__ __align__(16) u16 KTl[128][72];
  __shared__ __align__(16) u16 Pll4[4][16][72];
  u16 (*Pll)[72] = Pll4[wave];

  const int iq = i0 + (lm & 7);
  const int hh = h0 + wave * 2 + (lm >> 3);

  // ---- Q fragments (B-operand: col=lm=m, k=lg*8+j) ----
  const float qscale = 0.08838834764831845f;  // 1/sqrt(128)
  bf16x8 qf[4];
  {
    const float* qp = q + ((size_t)iq * H + hh) * D;
#pragma unroll
    for (int kt = 0; kt < 4; ++kt) {
      const float4* p4 = (const float4*)(qp + kt * 32 + lg * 8);
      float4 a = p4[0], b = p4[1];
      bf16x8 v;
      v[0] = (short)f2bf(a.x * qscale); v[1] = (short)f2bf(a.y * qscale);
      v[2] = (short)f2bf(a.z * qscale); v[3] = (short)f2bf(a.w * qscale);
      v[4] = (short)f2bf(b.x * qscale); v[5] = (short)f2bf(b.y * qscale);
      v[6] = (short)f2bf(b.z * qscale); v[7] = (short)f2bf(b.w * qscale);
      qf[kt] = v;
    }
  }

  const float sk = sink[hh];
  float m_run = sk, l_run = 0.f;
  f32x4 oacc[8];
  const f32x4 fzero = {0.f, 0.f, 0.f, 0.f};
#pragma unroll
  for (int b = 0; b < 8; ++b) oacc[b] = fzero;

  // ---- kv tiling (64-row tiles) ----
  const int w_lo = (i0 > WIN - 1) ? (i0 - (WIN - 1)) : 0;
  const int n1r = i0 + QB - w_lo;     // window rows (<=519)
  const int n2r = (i0 + QB) >> 2;     // compressed rows (<=512)
  const int nt1 = (n1r + KVB - 1) >> 6;
  const int nt2 = (n2r + KVB - 1) >> 6;
  const int ntiles = nt1 + nt2;

  // staging: 256 threads cover 64 rows x 128 cols; coalesced:
  // lanes 0..15 same 4-row group, cols 0..15
  const int st_dc = tid & 15;         // 8-col chunk
  const int st_t  = tid >> 4;         // 0..15, rows 4t..4t+3
  const int st_r0 = st_t * 4;

  uint4 sreg[4];   // 4 rows x 8 bf16
  auto sload = [&](int tt) {
    const int row0 = (tt < nt1) ? (w_lo + tt * KVB) : (2048 + (tt - nt1) * KVB);
    const u16* p = kvb + (size_t)(row0 + st_r0) * D + st_dc * 8;
#pragma unroll
    for (int rr = 0; rr < 4; ++rr)
      sreg[rr] = *(const uint4*)(p + (size_t)rr * D);
  };

  auto swrite = [&]() {
#pragma unroll
    for (int rr = 0; rr < 4; ++rr) {   // Ksub: kvgrp = st_t, row-XOR
      int rowp = rr ^ (st_t & 3);
      *(uint4*)&Ksub[st_t][st_dc >> 1][rowp][(st_dc & 1) * 8] = sreg[rr];
    }
    const u32* R0 = (const u32*)&sreg[0];
    const u32* R1 = (const u32*)&sreg[1];
    const u32* R2 = (const u32*)&sreg[2];
    const u32* R3 = (const u32*)&sreg[3];
#pragma unroll
    for (int dd2 = 0; dd2 < 4; ++dd2) {   // KT (V^T), d-XOR, v_perm repack
#pragma unroll
      for (int h = 0; h < 2; ++h) {
        const u32 sel = h ? 0x07060302u : 0x05040100u;
        u32 lo = __builtin_amdgcn_perm(R1[dd2], R0[dd2], sel);
        u32 hi = __builtin_amdgcn_perm(R3[dd2], R2[dd2], sel);
        int dl = st_dc * 8 + dd2 * 2 + h;
        int dphys = (dl & ~7) | ((dl & 7) ^ (st_dc & 7));
        *(uint2*)&KTl[dphys][st_r0] = make_uint2(lo, hi);
      }
    }
  };

  sload(0);   // prologue

  const int rrA = (lm & 3) ^ ((lm >> 2) & 3);

  for (int t = 0; t < ntiles; ++t) {
    __syncthreads();                   // buffer free (prev tile consumed)
    swrite();
    __syncthreads();                   // staged data visible
    if (t + 1 < ntiles) sload(t + 1);  // prefetch next tile (T14)

    const bool isw = t < nt1;
    const int row0 = isw ? (w_lo + t * KVB) : ((t - nt1) * KVB);  // mask-space

    // ---- T = K·Q^T (16 MFMA over kv 0..63) ----
    f32x4 tacc[4];
    tacc[0] = fzero; tacc[1] = fzero; tacc[2] = fzero; tacc[3] = fzero;
    __builtin_amdgcn_s_setprio(1);
#pragma unroll
    for (int kt = 0; kt < 4; ++kt) {
      const int ds = kt * 2 + (lg >> 1), co = (lg & 1) * 8;
#pragma unroll
      for (int k4 = 0; k4 < 4; ++k4) {
        bf16x8 a = *(const bf16x8*)&Ksub[k4 * 4 + (lm >> 2)][ds][rrA][co];
        tacc[k4] = __builtin_amdgcn_mfma_f32_16x16x32_bf16(a, qf[kt], tacc[k4], 0, 0, 0);
      }
    }
    __builtin_amdgcn_s_setprio(0);

    // ---- mask (wave-uniform fast path) + online softmax (state at lane=m) ----
    float vv[16];
    float tm = -1e30f;
    const bool fullv = isw ? (row0 >= i0 + (QB - 1) - (WIN - 1)) && (row0 + KVB - 1 <= i0)
                           : ((row0 + KVB - 1) * 4 + 3 <= i0);
    if (fullv) {
#pragma unroll
      for (int k4 = 0; k4 < 4; ++k4)
#pragma unroll
        for (int r = 0; r < 4; ++r) {
          float x = tacc[k4][r];
          vv[k4 * 4 + r] = x;
          tm = fmaxf(tm, x);
        }
    } else {
#pragma unroll
      for (int k4 = 0; k4 < 4; ++k4)
#pragma unroll
        for (int r = 0; r < 4; ++r) {
          int jj = row0 + k4 * 16 + lg * 4 + r;
          float x = tacc[k4][r];
          bool ok = isw ? (jj <= iq && jj + WIN > iq) : (jj * 4 + 3 <= iq);
          x = ok ? x : -1e30f;
          vv[k4 * 4 + r] = x;
          tm = fmaxf(tm, x);
        }
    }
    tm = fmaxf(tm, __shfl_xor(tm, 16));
    tm = fmaxf(tm, __shfl_xor(tm, 32));
    if (__any(tm > m_run + 8.f)) {       // defer-max (T13)
      float mn = fmaxf(m_run, tm);
      float fs = __expf(m_run - mn);
      m_run = mn; l_run *= fs;
#pragma unroll
      for (int dt = 0; dt < 8; ++dt) oacc[dt] *= fs;
    }
    float s = 0.f;
#pragma unroll
    for (int k4 = 0; k4 < 4; ++k4) {
      u16 pb[4];
#pragma unroll
      for (int r = 0; r < 4; ++r) {
        float p = __expf(vv[k4 * 4 + r] - m_run);
        s += p; pb[r] = f2bf(p);
      }
      *(uint2*)&Pll[lm][k4 * 16 + lg * 4] =
          make_uint2((u32)pb[0] | ((u32)pb[1] << 16),
                     (u32)pb[2] | ((u32)pb[3] << 16));
    }
    l_run += s;

    // ---- O^T += V^T·P (16 MFMA over kv 0..63) ----
    bf16x8 pf0 = *(const bf16x8*)&Pll[lm][lg * 8];
    bf16x8 pf1 = *(const bf16x8*)&Pll[lm][32 + lg * 8];
    __builtin_amdgcn_s_setprio(1);
#pragma unroll
    for (int dt = 0; dt < 8; ++dt) {
      int d = dt * 16 + lm;
      int drow = (d & ~7) | ((d & 7) ^ ((d >> 3) & 7));
      bf16x8 vf0 = *(const bf16x8*)&KTl[drow][lg * 8];
      bf16x8 vf1 = *(const bf16x8*)&KTl[drow][32 + lg * 8];
      oacc[dt] = __builtin_amdgcn_mfma_f32_16x16x32_bf16(vf0, pf0, oacc[dt], 0, 0, 0);
      oacc[dt] = __builtin_amdgcn_mfma_f32_16x16x32_bf16(vf1, pf1, oacc[dt], 0, 0, 0);
    }
    __builtin_amdgcn_s_setprio(0);
  }

  // ---- epilogue (no split merge needed) ----
  float l = l_run;
  l += __shfl_xor(l, 16);
  l += __shfl_xor(l, 32);
  l += __expf(sk - m_run);   // sink joins the denominator
  float di = 1.f / l;
  float* op = out + ((size_t)iq * H + hh) * D;
#pragma unroll
  for (int dt = 0; dt < 8; ++dt) {
    f32x4 o = oacc[dt];
    float4 w4 = make_float4(o[0] * di, o[1] * di, o[2] * di, o[3] * di);
    *(float4*)(op + dt * 16 + lg * 4) = w4;
  }
}

extern "C" void kernel_launch(void* const* d_in, const int* in_sizes, int n_in,
                              void* d_out, int out_size, void* d_ws, size_t ws_size,
                              hipStream_t stream) {
  const float* q    = (const float*)d_in[0];
  const float* kvs  = (const float*)d_in[1];
  const float* sink = (const float*)d_in[2];
  const float* kvc  = (const float*)d_in[3];
  float* out = (float*)d_out;
  u16* kvb = (u16*)d_ws;   // 2592*128*2 = 663,552 B

  {
    int nthr = KVROWS * (D / 8);
    precvt_kv<<<(nthr + 255) / 256, 256, 0, stream>>>(kvs, kvc, kvb);
  }
  dim3 grid(S / QB, H / HG);   // 256 x 2 = 512 blocks
  sparse_attn_mfma8<<<grid, NT, 0, stream>>>(q, kvb, sink, out);
}